// Round 18
// baseline (363.810 us; speedup 1.0000x reference)
//
#include <hip/hip_runtime.h>
#include <hip/hip_bf16.h>
#include <math.h>

#define T_TOK 1024
#define H_DIM 2048
#define I_DIM 768
#define E_NUM 32
#define K_TOP 8
#define BK 64
#define GRID_P 512   // 2 blocks/CU (64 KB LDS each)

typedef __bf16 bf16x8 __attribute__((ext_vector_type(8)));
typedef float  f32x4  __attribute__((ext_vector_type(4)));

__device__ __forceinline__ bf16x8 cvt2_bf16(const f32x4 a, const f32x4 b) {
    bf16x8 r;
    r[0] = (__bf16)a[0]; r[1] = (__bf16)a[1]; r[2] = (__bf16)a[2]; r[3] = (__bf16)a[3];
    r[4] = (__bf16)b[0]; r[5] = (__bf16)b[1]; r[6] = (__bf16)b[2]; r[7] = (__bf16)b[3];
    return r;
}

// LDS fragment-order layout, two 32-k subtiles per 64-k step: element
// (r, k) at (k>>5)*4096 + (r>>4)*512 + ((k&31)>>3)*128 + (r&15)*8 + (k&7).
// Wave fragment read = subtile base + lane*8 (16B/lane, linear).
__device__ __forceinline__ int frag_off(int r) {     // base for kgrp8=0
    return (r >> 4) * 512 + (r & 15) * 8;
}

// ---------------- Router: logits -> top-8 weights; also emits xb (bf16 x) ---
__global__ __launch_bounds__(256) void router_kernel(
    const float* __restrict__ x, const float* __restrict__ gw,
    float* __restrict__ wdense, unsigned int* __restrict__ masks,
    __bf16* __restrict__ xb)
{
    const int t = blockIdx.x;
    const int tid = threadIdx.x;
    __shared__ float xrow[H_DIM];
    __shared__ float part[256];
    __shared__ float logits[E_NUM];

    {
        const float* xr2 = x + (size_t)t * H_DIM + tid * 8;
        const f32x4 a = *(const f32x4*)(xr2);
        const f32x4 b = *(const f32x4*)(xr2 + 4);
        *(f32x4*)(xrow + tid * 8)     = a;
        *(f32x4*)(xrow + tid * 8 + 4) = b;
        *(bf16x8*)(xb + (size_t)t * H_DIM + tid * 8) = cvt2_bf16(a, b);
    }
    __syncthreads();

    const int e = tid & 31;
    const int chunk = tid >> 5;
    const float* gr = gw + (size_t)e * H_DIM;
    const int base = chunk * (H_DIM / 8);
    float s = 0.f;
    for (int h = 0; h < H_DIM / 8; h += 4) {
        const f32x4 xv = *(const f32x4*)(xrow + base + h);
        const f32x4 gv = *(const f32x4*)(gr + base + h);
        s += xv[0]*gv[0] + xv[1]*gv[1] + xv[2]*gv[2] + xv[3]*gv[3];
    }
    part[tid] = s;
    __syncthreads();
    if (tid < E_NUM) {
        float tot = 0.f;
        for (int c = 0; c < 8; ++c) tot += part[c * 32 + tid];
        logits[tid] = tot;
    }
    __syncthreads();
    if (tid == 0) {
        float l[E_NUM];
        for (int i = 0; i < E_NUM; ++i) {
            l[i] = logits[i];
            wdense[(size_t)t * E_NUM + i] = 0.f;
        }
        unsigned mask = 0;
        int   idx[K_TOP];
        float lv[K_TOP];
        for (int k = 0; k < K_TOP; ++k) {
            float best = -1e30f; int bi = 0;
            for (int i = 0; i < E_NUM; ++i)
                if (!((mask >> i) & 1u) && l[i] > best) { best = l[i]; bi = i; }
            mask |= (1u << bi); idx[k] = bi; lv[k] = best;
        }
        const float m = lv[0];
        float den = 0.f;
        for (int k = 0; k < K_TOP; ++k) den += expf(lv[k] - m);
        for (int k = 0; k < K_TOP; ++k)
            wdense[(size_t)t * E_NUM + idx[k]] = expf(lv[k] - m) / den;
        masks[t] = mask;
    }
}

// ---------------- Fused routing tables --------------------------------------
__global__ __launch_bounds__(1024) void route_kernel(
    const unsigned int* __restrict__ masks, const float* __restrict__ wdense,
    int* __restrict__ cnt, int* __restrict__ off, int* __restrict__ tbl,
    int* __restrict__ tok, float* __restrict__ wgt, int* __restrict__ posl)
{
    const int tid  = threadIdx.x;
    const int wv   = tid >> 6;
    const int lane = tid & 63;
    __shared__ int wcnt[E_NUM][16];
    __shared__ int woff[E_NUM][16];
    __shared__ int eoff[E_NUM];
    __shared__ int ecnt[E_NUM];

    const unsigned int m = masks[tid];
#pragma unroll
    for (int e = 0; e < E_NUM; ++e) {
        const unsigned long long b = __ballot((m >> e) & 1u);
        if (lane == 0) wcnt[e][wv] = __popcll(b);
    }
    __syncthreads();
    if (tid < E_NUM) {
        int r = 0;
        for (int w = 0; w < 16; ++w) { woff[tid][w] = r; r += wcnt[tid][w]; }
        ecnt[tid] = r;
    }
    __syncthreads();
    if (tid == 0) {
        int r = 0, nt = 0;
        for (int e = 0; e < E_NUM; ++e) {
            eoff[e] = r; off[e] = r;
            const int c = ecnt[e];
            cnt[e] = c;
            r += c;
            const int nz = (c + 127) >> 7;
            for (int z = 0; z < nz; ++z) tbl[1 + nt++] = (e << 8) | z;
        }
        tbl[0] = nt;
    }
    __syncthreads();
#pragma unroll
    for (int e = 0; e < E_NUM; ++e) {
        const int bit = (m >> e) & 1u;
        const unsigned long long b = __ballot(bit);
        if (bit) {
            const int pos = eoff[e] + woff[e][wv]
                          + (int)__popcll(b & ((1ULL << lane) - 1ULL));
            tok[pos] = tid;
            wgt[pos] = wdense[(size_t)tid * E_NUM + e];
            const int slot = __popc(m & ((1u << e) - 1u));
            posl[tid * K_TOP + slot] = pos;
        }
    }
}

// BK=64 phase: prefetch step scur+2 into regset P (A 4x bf16x8, B 8x f32x4),
// ds_read+32 MFMA from buf P (two 32-k subtiles), write regset Q (=scur+1)
// into buf Q, lgkmcnt(0)+raw barrier. Half the barriers of BK=32; loads stay
// in flight across the barrier (compiler-counted vmcnt at the ds_write).
// (256,2): 2 blocks/CU, reg cap 256/wave -> ~200 used, no spill.
#define GEMM_PHASE(P, Q)                                                       \
  {                                                                            \
    if (scur + 2 < NS) {                                                       \
      const int kk = (scur + 2) * BK;                                          \
      pa##P##_0 = *(const bf16x8*)(ap + kk);                                   \
      pa##P##_1 = *(const bf16x8*)(ap + kk + 8);                               \
      pa##P##_2 = *(const bf16x8*)(ap + kk + 16);                              \
      pa##P##_3 = *(const bf16x8*)(ap + kk + 24);                              \
      pb##P##_0 = *(const f32x4*)(wp + kk);                                    \
      pb##P##_1 = *(const f32x4*)(wp + kk + 4);                                \
      pb##P##_2 = *(const f32x4*)(wp + kk + 8);                                \
      pb##P##_3 = *(const f32x4*)(wp + kk + 12);                               \
      pb##P##_4 = *(const f32x4*)(wp + kk + 16);                               \
      pb##P##_5 = *(const f32x4*)(wp + kk + 20);                               \
      pb##P##_6 = *(const f32x4*)(wp + kk + 24);                               \
      pb##P##_7 = *(const f32x4*)(wp + kk + 28);                               \
    }                                                                          \
    bf16x8 af[8], bfr[8];                                                      \
    _Pragma("unroll")                                                          \
    for (int ks = 0; ks < 2; ++ks) {                                           \
      _Pragma("unroll")                                                        \
      for (int m = 0; m < 4; ++m)                                              \
        af[ks * 4 + m] = *(const bf16x8*)                                      \
            &As[P][ks * 4096 + ((wm >> 4) + m) * 512 + lane * 8];              \
      _Pragma("unroll")                                                        \
      for (int n = 0; n < 4; ++n)                                              \
        bfr[ks * 4 + n] = *(const bf16x8*)                                     \
            &Bs[P][ks * 4096 + (wn * 4 + n) * 512 + lane * 8];                 \
    }                                                                          \
    _Pragma("unroll")                                                          \
    for (int ks = 0; ks < 2; ++ks)                                             \
      _Pragma("unroll")                                                        \
      for (int m = 0; m < 4; ++m)                                              \
        _Pragma("unroll")                                                      \
        for (int n = 0; n < 4; ++n)                                            \
          acc[m][n] = __builtin_amdgcn_mfma_f32_16x16x32_bf16(                 \
              af[ks * 4 + m], bfr[ks * 4 + n], acc[m][n], 0, 0, 0);            \
    if (scur + 1 < NS) {                                                       \
      *(bf16x8*)&As[Q][wo]       = pa##Q##_0;                                  \
      *(bf16x8*)&As[Q][wo + 128] = pa##Q##_1;                                  \
      *(bf16x8*)&As[Q][wo + 256] = pa##Q##_2;                                  \
      *(bf16x8*)&As[Q][wo + 384] = pa##Q##_3;                                  \
      *(bf16x8*)&Bs[Q][wo]       = cvt2_bf16(pb##Q##_0, pb##Q##_1);            \
      *(bf16x8*)&Bs[Q][wo + 128] = cvt2_bf16(pb##Q##_2, pb##Q##_3);            \
      *(bf16x8*)&Bs[Q][wo + 256] = cvt2_bf16(pb##Q##_4, pb##Q##_5);            \
      *(bf16x8*)&Bs[Q][wo + 384] = cvt2_bf16(pb##Q##_6, pb##Q##_7);            \
    }                                                                          \
    asm volatile("s_waitcnt lgkmcnt(0)" ::: "memory");                         \
    __builtin_amdgcn_s_barrier();                                              \
    ++scur;                                                                    \
  }

#define GEMM_REGS                                                              \
    bf16x8 pa0_0, pa0_1, pa0_2, pa0_3, pa1_0, pa1_1, pa1_2, pa1_3;             \
    f32x4  pb0_0, pb0_1, pb0_2, pb0_3, pb0_4, pb0_5, pb0_6, pb0_7;             \
    f32x4  pb1_0, pb1_1, pb1_2, pb1_3, pb1_4, pb1_5, pb1_6, pb1_7;

#define GEMM_PROLOGUE()                                                        \
    pa0_0 = *(const bf16x8*)(ap);                                              \
    pa0_1 = *(const bf16x8*)(ap + 8);                                          \
    pa0_2 = *(const bf16x8*)(ap + 16);                                         \
    pa0_3 = *(const bf16x8*)(ap + 24);                                         \
    pb0_0 = *(const f32x4*)(wp);                                               \
    pb0_1 = *(const f32x4*)(wp + 4);                                           \
    pb0_2 = *(const f32x4*)(wp + 8);                                           \
    pb0_3 = *(const f32x4*)(wp + 12);                                          \
    pb0_4 = *(const f32x4*)(wp + 16);                                          \
    pb0_5 = *(const f32x4*)(wp + 20);                                          \
    pb0_6 = *(const f32x4*)(wp + 24);                                          \
    pb0_7 = *(const f32x4*)(wp + 28);                                          \
    pa1_0 = *(const bf16x8*)(ap + BK);                                         \
    pa1_1 = *(const bf16x8*)(ap + BK + 8);                                     \
    pa1_2 = *(const bf16x8*)(ap + BK + 16);                                    \
    pa1_3 = *(const bf16x8*)(ap + BK + 24);                                    \
    pb1_0 = *(const f32x4*)(wp + BK);                                          \
    pb1_1 = *(const f32x4*)(wp + BK + 4);                                      \
    pb1_2 = *(const f32x4*)(wp + BK + 8);                                      \
    pb1_3 = *(const f32x4*)(wp + BK + 12);                                     \
    pb1_4 = *(const f32x4*)(wp + BK + 16);                                     \
    pb1_5 = *(const f32x4*)(wp + BK + 20);                                     \
    pb1_6 = *(const f32x4*)(wp + BK + 24);                                     \
    pb1_7 = *(const f32x4*)(wp + BK + 28);                                     \
    *(bf16x8*)&As[0][wo]       = pa0_0;                                        \
    *(bf16x8*)&As[0][wo + 128] = pa0_1;                                        \
    *(bf16x8*)&As[0][wo + 256] = pa0_2;                                        \
    *(bf16x8*)&As[0][wo + 384] = pa0_3;                                        \
    *(bf16x8*)&Bs[0][wo]       = cvt2_bf16(pb0_0, pb0_1);                      \
    *(bf16x8*)&Bs[0][wo + 128] = cvt2_bf16(pb0_2, pb0_3);                      \
    *(bf16x8*)&Bs[0][wo + 256] = cvt2_bf16(pb0_4, pb0_5);                      \
    *(bf16x8*)&Bs[0][wo + 384] = cvt2_bf16(pb0_6, pb0_7);                      \
    asm volatile("s_waitcnt lgkmcnt(0)" ::: "memory");                         \
    __builtin_amdgcn_s_barrier();

// ---------------- GEMM1: act = silu(x @ w1^T) * (x @ w3^T) ------------------
// Persistent, XCD-chunked nidx-major. Tile: 128 tok x 128 Brows, BK=64.
// Staging: thread (sr=tid>>1, kh=tid&1) owns 32 k-elems of row sr.
__global__ __launch_bounds__(256, 2) void gemm1_kernel(
    const __bf16* __restrict__ xb, const float* __restrict__ w13,
    const int* __restrict__ tok, const int* __restrict__ cnt,
    const int* __restrict__ off, const int* __restrict__ tbl,
    unsigned short* __restrict__ act)
{
    __shared__ __bf16 As[2][8192];
    __shared__ __bf16 Bs[2][8192];
    const int tid  = threadIdx.x;
    const int wid  = tid >> 6;
    const int lane = tid & 63;
    const int wm = (wid >> 1) * 64;
    const int wn = (wid & 1);
    const int lrow = lane & 15;
    const int sr = tid >> 1;
    const int kh = tid & 1;
    const int wo = kh * 4096 + frag_off(sr);
    const int NS = H_DIM / BK;   // 32

    const int NT = tbl[0];
    const int W  = NT * 12;
    const int slab = (W + 7) >> 3;
    const int xcd  = blockIdx.x & 7;
    const int jj   = blockIdx.x >> 3;
    const int wlo  = xcd * slab;
    const int whi  = (wlo + slab) < W ? (wlo + slab) : W;
    for (int w = wlo + jj; w < whi; w += GRID_P / 8) {
        const int nidx = w / NT;
        const int ti   = w - nidx * NT;
        const int ez = tbl[1 + ti];
        const int e  = ez >> 8;
        const int m0 = (ez & 255) * 128;
        const int c  = cnt[e];
        const int o  = off[e];
        const int n0 = nidx * 64;

        int rA = m0 + sr; rA = rA < c ? rA : c - 1;
        const __bf16* ap = xb + (size_t)tok[o + rA] * H_DIM + kh * 32;
        const int grp = sr >> 5;
        const int wrow = (grp & 1) * I_DIM + n0 + (grp >> 1) * 32 + (sr & 31);
        const float* wp = w13 + (size_t)e * (2 * I_DIM) * H_DIM
                              + (size_t)wrow * H_DIM + kh * 32;

        GEMM_REGS
        f32x4 acc[4][4] = {};

        GEMM_PROLOGUE()

        int scur = 0;
        for (int it = 0; it < NS; it += 2) {
            GEMM_PHASE(0, 1)
            GEMM_PHASE(1, 0)
        }

        // epilogue: n=0,1 gate, n=2,3 up; icol = n0 + wn*32 + n*16 + lrow
#pragma unroll
        for (int m = 0; m < 4; ++m)
#pragma unroll
            for (int n = 0; n < 2; ++n)
#pragma unroll
                for (int i = 0; i < 4; ++i) {
                    const int row = m0 + wm + m * 16 + (lane >> 4) * 4 + i;
                    if (row < c) {
                        const int icol = n0 + wn * 32 + n * 16 + lrow;
                        const float g = acc[m][n][i];
                        const float u = acc[m][n + 2][i];
                        const float a = (g / (1.f + expf(-g))) * u;
                        act[(size_t)(o + row) * I_DIM + icol] =
                            __builtin_bit_cast(unsigned short, (__bf16)a);
                    }
                }
    }
}

// ---------------- GEMM2: ybuf[o+row] = wgt * (act @ w2^T), bf16 partials ----
// Persistent, XCD-chunked nidx-major. Tile: 128 tok x 128 H-cols, BK=64.
__global__ __launch_bounds__(256, 2) void gemm2_kernel(
    const unsigned short* __restrict__ act, const float* __restrict__ w2,
    const int* __restrict__ tok, const float* __restrict__ wgt,
    const int* __restrict__ cnt, const int* __restrict__ off,
    const int* __restrict__ tbl, unsigned short* __restrict__ ybuf)
{
    __shared__ __bf16 As[2][8192];
    __shared__ __bf16 Bs[2][8192];
    const int tid  = threadIdx.x;
    const int wid  = tid >> 6;
    const int lane = tid & 63;
    const int wm = (wid >> 1) * 64;
    const int wn = (wid & 1);
    const int lrow = lane & 15;
    const int sr = tid >> 1;
    const int kh = tid & 1;
    const int wo = kh * 4096 + frag_off(sr);
    const int NS = I_DIM / BK;   // 12

    const int NT = tbl[0];
    const int W  = NT * 16;
    const int slab = (W + 7) >> 3;
    const int xcd  = blockIdx.x & 7;
    const int jj   = blockIdx.x >> 3;
    const int wlo  = xcd * slab;
    const int whi  = (wlo + slab) < W ? (wlo + slab) : W;
    for (int w = wlo + jj; w < whi; w += GRID_P / 8) {
        const int nidx = w / NT;
        const int ti   = w - nidx * NT;
        const int ez = tbl[1 + ti];
        const int e  = ez >> 8;
        const int m0 = (ez & 255) * 128;
        const int c  = cnt[e];
        const int o  = off[e];
        const int n0 = nidx * 128;

        int rA = m0 + sr; rA = rA < c ? rA : c - 1;
        const __bf16* ap = (const __bf16*)act + (size_t)(o + rA) * I_DIM + kh * 32;
        const float* wp = w2 + (size_t)e * H_DIM * I_DIM
                             + (size_t)(n0 + sr) * I_DIM + kh * 32;

        GEMM_REGS
        f32x4 acc[4][4] = {};

        GEMM_PROLOGUE()

        int scur = 0;
        for (int it = 0; it < NS; it += 2) {
            GEMM_PHASE(0, 1)
            GEMM_PHASE(1, 0)
        }

        // epilogue: weighted partial rows, bf16 stores (no RMW)
#pragma unroll
        for (int m = 0; m < 4; ++m)
#pragma unroll
            for (int i = 0; i < 4; ++i) {
                const int row = m0 + wm + m * 16 + (lane >> 4) * 4 + i;
                if (row < c) {
                    const float wv = wgt[o + row];
                    unsigned short* yr = ybuf + (size_t)(o + row) * H_DIM
                                              + n0 + wn * 64 + lrow;
#pragma unroll
                    for (int n = 0; n < 4; ++n)
                        yr[n * 16] = __builtin_bit_cast(
                            unsigned short, (__bf16)(wv * acc[m][n][i]));
                }
            }
    }
}

// ---------------- Combine: out[t] = sum_s ybuf[posl[t*8+s]] (bf16 -> f32) ---
__global__ __launch_bounds__(256) void combine_kernel(
    const unsigned short* __restrict__ ybuf, const int* __restrict__ posl,
    float* __restrict__ out)
{
    const int t = blockIdx.x;
    int p[K_TOP];
#pragma unroll
    for (int s = 0; s < K_TOP; ++s) p[s] = posl[t * K_TOP + s];
    const int h0 = threadIdx.x * 8;
    float a[8] = {};
#pragma unroll
    for (int s = 0; s < K_TOP; ++s) {
        const bf16x8 v = *(const bf16x8*)(ybuf + (size_t)p[s] * H_DIM + h0);
#pragma unroll
        for (int j = 0; j < 8; ++j) a[j] += (float)v[j];
    }
    f32x4 o0 = {a[0], a[1], a[2], a[3]};
    f32x4 o1 = {a[4], a[5], a[6], a[7]};
    *(f32x4*)(out + (size_t)t * H_DIM + h0)     = o0;
    *(f32x4*)(out + (size_t)t * H_DIM + h0 + 4) = o1;
}

// ---------------- Launch ----------------------------------------------------
extern "C" void kernel_launch(void* const* d_in, const int* in_sizes, int n_in,
                              void* d_out, int out_size, void* d_ws, size_t ws_size,
                              hipStream_t stream)
{
    const float* x   = (const float*)d_in[0];
    const float* gw  = (const float*)d_in[1];
    const float* w13 = (const float*)d_in[2];
    const float* w2  = (const float*)d_in[3];
    float* out = (float*)d_out;

    char* ws = (char*)d_ws;
    float*          wdense = (float*)(ws + 0x00000);
    unsigned int*   masks  = (unsigned int*)(ws + 0x20000);
    int*            cnt    = (int*)(ws + 0x21000);
    int*            off    = (int*)(ws + 0x21800);
    int*            tbl    = (int*)(ws + 0x22000);
    int*            tok    = (int*)(ws + 0x23000);
    float*          wgt    = (float*)(ws + 0x2B000);
    unsigned short* act    = (unsigned short*)(ws + 0x33000);    // 12.6 MB
    __bf16*         xb     = (__bf16*)(ws + 0xC40000);           // 4 MB
    int*            posl   = (int*)(ws + 0x1040000);             // 32 KB
    unsigned short* ybuf   = (unsigned short*)(ws + 0x1100000);  // 33.5 MB

    router_kernel<<<T_TOK, 256, 0, stream>>>(x, gw, wdense, masks, xb);
    route_kernel<<<1, 1024, 0, stream>>>(masks, wdense, cnt, off, tbl, tok, wgt, posl);
    gemm1_kernel<<<GRID_P, 256, 0, stream>>>(xb, w13, tok, cnt, off, tbl, act);
    gemm2_kernel<<<GRID_P, 256, 0, stream>>>(act, w2, tok, wgt, cnt, off, tbl, ybuf);
    combine_kernel<<<T_TOK, 256, 0, stream>>>(ybuf, posl, out);
}

// Round 19
// 332.283 us; speedup vs baseline: 1.0949x; 1.0949x over previous
//
#include <hip/hip_runtime.h>
#include <hip/hip_bf16.h>
#include <math.h>

#define T_TOK 1024
#define H_DIM 2048
#define I_DIM 768
#define E_NUM 32
#define K_TOP 8
#define BK 32
#define GRID_P 1024

typedef __bf16 bf16x8 __attribute__((ext_vector_type(8)));
typedef float  f32x4  __attribute__((ext_vector_type(4)));

__device__ __forceinline__ bf16x8 cvt2_bf16(const f32x4 a, const f32x4 b) {
    bf16x8 r;
    r[0] = (__bf16)a[0]; r[1] = (__bf16)a[1]; r[2] = (__bf16)a[2]; r[3] = (__bf16)a[3];
    r[4] = (__bf16)b[0]; r[5] = (__bf16)b[1]; r[6] = (__bf16)b[2]; r[7] = (__bf16)b[3];
    return r;
}

// LDS fragment-order layout (128 rows x 32 k bf16): element (r,k) at
// (r>>4)*512 + (k>>3)*128 + (r&15)*8 + (k&7). Wave fragment read =
// subtile*512 + lane*8 (16B/lane, linear).
__device__ __forceinline__ int frag_off(int r, int kgrp8) {
    return (r >> 4) * 512 + kgrp8 * 128 + (r & 15) * 8;
}

// ---------------- Router: logits -> top-8 weights; also emits xb (bf16 x) ---
// x row staged in LDS once (was re-read 32x from L2, once per expert lane).
__global__ __launch_bounds__(256) void router_kernel(
    const float* __restrict__ x, const float* __restrict__ gw,
    float* __restrict__ wdense, unsigned int* __restrict__ masks,
    __bf16* __restrict__ xb)
{
    const int t = blockIdx.x;
    const int tid = threadIdx.x;
    __shared__ float xrow[H_DIM];
    __shared__ float part[256];
    __shared__ float logits[E_NUM];

    // stage row t to LDS + write bf16 copy (fold of cvtx)
    {
        const float* xr2 = x + (size_t)t * H_DIM + tid * 8;
        const f32x4 a = *(const f32x4*)(xr2);
        const f32x4 b = *(const f32x4*)(xr2 + 4);
        *(f32x4*)(xrow + tid * 8)     = a;
        *(f32x4*)(xrow + tid * 8 + 4) = b;
        *(bf16x8*)(xb + (size_t)t * H_DIM + tid * 8) = cvt2_bf16(a, b);
    }
    __syncthreads();

    const int e = tid & 31;
    const int chunk = tid >> 5;
    const float* gr = gw + (size_t)e * H_DIM;
    const int base = chunk * (H_DIM / 8);
    float s = 0.f;
    for (int h = 0; h < H_DIM / 8; h += 4) {
        const f32x4 xv = *(const f32x4*)(xrow + base + h);   // LDS broadcast
        const f32x4 gv = *(const f32x4*)(gr + base + h);
        s += xv[0]*gv[0] + xv[1]*gv[1] + xv[2]*gv[2] + xv[3]*gv[3];
    }
    part[tid] = s;
    __syncthreads();
    if (tid < E_NUM) {
        float tot = 0.f;
        for (int c = 0; c < 8; ++c) tot += part[c * 32 + tid];
        logits[tid] = tot;
    }
    __syncthreads();
    if (tid == 0) {
        float l[E_NUM];
        for (int i = 0; i < E_NUM; ++i) {
            l[i] = logits[i];
            wdense[(size_t)t * E_NUM + i] = 0.f;
        }
        unsigned mask = 0;
        int   idx[K_TOP];
        float lv[K_TOP];
        for (int k = 0; k < K_TOP; ++k) {
            float best = -1e30f; int bi = 0;
            for (int i = 0; i < E_NUM; ++i)
                if (!((mask >> i) & 1u) && l[i] > best) { best = l[i]; bi = i; }
            mask |= (1u << bi); idx[k] = bi; lv[k] = best;
        }
        const float m = lv[0];
        float den = 0.f;
        for (int k = 0; k < K_TOP; ++k) den += expf(lv[k] - m);
        for (int k = 0; k < K_TOP; ++k)
            wdense[(size_t)t * E_NUM + idx[k]] = expf(lv[k] - m) / den;
        masks[t] = mask;
    }
}

// ---------------- Fused routing tables (replaces count+scan+fill) -----------
// One block, 1024 threads (thread == token). Ballot-based rank; deterministic
// ascending-token order per expert.
__global__ __launch_bounds__(1024) void route_kernel(
    const unsigned int* __restrict__ masks, const float* __restrict__ wdense,
    int* __restrict__ cnt, int* __restrict__ off, int* __restrict__ tbl,
    int* __restrict__ tok, float* __restrict__ wgt, int* __restrict__ posl)
{
    const int tid  = threadIdx.x;      // token id
    const int wv   = tid >> 6;         // wave 0..15
    const int lane = tid & 63;
    __shared__ int wcnt[E_NUM][16];
    __shared__ int woff[E_NUM][16];
    __shared__ int eoff[E_NUM];
    __shared__ int ecnt[E_NUM];

    const unsigned int m = masks[tid];
#pragma unroll
    for (int e = 0; e < E_NUM; ++e) {
        const unsigned long long b = __ballot((m >> e) & 1u);
        if (lane == 0) wcnt[e][wv] = __popcll(b);
    }
    __syncthreads();
    if (tid < E_NUM) {
        int r = 0;
        for (int w = 0; w < 16; ++w) { woff[tid][w] = r; r += wcnt[tid][w]; }
        ecnt[tid] = r;
    }
    __syncthreads();
    if (tid == 0) {
        int r = 0, nt = 0;
        for (int e = 0; e < E_NUM; ++e) {
            eoff[e] = r; off[e] = r;
            const int c = ecnt[e];
            cnt[e] = c;
            r += c;
            const int nz = (c + 127) >> 7;
            for (int z = 0; z < nz; ++z) tbl[1 + nt++] = (e << 8) | z;
        }
        tbl[0] = nt;
    }
    __syncthreads();
#pragma unroll
    for (int e = 0; e < E_NUM; ++e) {
        const int bit = (m >> e) & 1u;
        const unsigned long long b = __ballot(bit);
        if (bit) {
            const int pos = eoff[e] + woff[e][wv]
                          + (int)__popcll(b & ((1ULL << lane) - 1ULL));
            tok[pos] = tid;
            wgt[pos] = wdense[(size_t)tid * E_NUM + e];
            const int slot = __popc(m & ((1u << e) - 1u));
            posl[tid * K_TOP + slot] = pos;
        }
    }
}

// Phase macro (round-10 verified anchor): prefetch step scur+2 into regset P,
// MFMA from buf P, write regset Q (=step scur+1) into buf Q. lgkmcnt(0)+raw
// barrier only; global loads stay in flight across the barrier (compiler
// inserts the counted vmcnt before the ds_write that consumes them).
// NOTE: this core is bracketed in all four directions — (256,4) spills (r13),
// depth-3 spills (r14), BK=64 loses occupancy (r18), gload_lds/fences (r12)
// and setprio (r16) null/negative. Do not perturb without new evidence.
#define GEMM_PHASE(P, Q)                                                       \
  {                                                                            \
    if (scur + 2 < NS) {                                                       \
      const int kk = (scur + 2) * BK;                                          \
      pa##P##_0 = *(const bf16x8*)(ap + kk);                                   \
      pa##P##_1 = *(const bf16x8*)(ap + kk + 8);                               \
      pb##P##_0 = *(const f32x4*)(wp + kk);                                    \
      pb##P##_1 = *(const f32x4*)(wp + kk + 4);                                \
      pb##P##_2 = *(const f32x4*)(wp + kk + 8);                                \
      pb##P##_3 = *(const f32x4*)(wp + kk + 12);                               \
    }                                                                          \
    bf16x8 af[4], bfr[4];                                                      \
    _Pragma("unroll")                                                          \
    for (int m = 0; m < 4; ++m)                                                \
      af[m] = *(const bf16x8*)&As[P][((wm >> 4) + m) * 512 + lane * 8];        \
    _Pragma("unroll")                                                          \
    for (int n = 0; n < 4; ++n)                                                \
      bfr[n] = *(const bf16x8*)&Bs[P][(wn * 4 + n) * 512 + lane * 8];          \
    _Pragma("unroll")                                                          \
    for (int m = 0; m < 4; ++m)                                                \
      _Pragma("unroll")                                                        \
      for (int n = 0; n < 4; ++n)                                              \
        acc[m][n] = __builtin_amdgcn_mfma_f32_16x16x32_bf16(af[m], bfr[n],     \
                                                            acc[m][n], 0,0,0); \
    if (scur + 1 < NS) {                                                       \
      *(bf16x8*)&As[Q][wo]       = pa##Q##_0;                                  \
      *(bf16x8*)&As[Q][wo + 128] = pa##Q##_1;                                  \
      *(bf16x8*)&Bs[Q][wo]       = cvt2_bf16(pb##Q##_0, pb##Q##_1);            \
      *(bf16x8*)&Bs[Q][wo + 128] = cvt2_bf16(pb##Q##_2, pb##Q##_3);            \
    }                                                                          \
    asm volatile("s_waitcnt lgkmcnt(0)" ::: "memory");                         \
    __builtin_amdgcn_s_barrier();                                              \
    ++scur;                                                                    \
  }

#define GEMM_PROLOGUE()                                                        \
    pa0_0 = *(const bf16x8*)(ap);                                              \
    pa0_1 = *(const bf16x8*)(ap + 8);                                          \
    pb0_0 = *(const f32x4*)(wp);                                               \
    pb0_1 = *(const f32x4*)(wp + 4);                                           \
    pb0_2 = *(const f32x4*)(wp + 8);                                           \
    pb0_3 = *(const f32x4*)(wp + 12);                                          \
    pa1_0 = *(const bf16x8*)(ap + BK);                                         \
    pa1_1 = *(const bf16x8*)(ap + BK + 8);                                     \
    pb1_0 = *(const f32x4*)(wp + BK);                                          \
    pb1_1 = *(const f32x4*)(wp + BK + 4);                                      \
    pb1_2 = *(const f32x4*)(wp + BK + 8);                                      \
    pb1_3 = *(const f32x4*)(wp + BK + 12);                                     \
    *(bf16x8*)&As[0][wo]       = pa0_0;                                        \
    *(bf16x8*)&As[0][wo + 128] = pa0_1;                                        \
    *(bf16x8*)&Bs[0][wo]       = cvt2_bf16(pb0_0, pb0_1);                      \
    *(bf16x8*)&Bs[0][wo + 128] = cvt2_bf16(pb0_2, pb0_3);                      \
    asm volatile("s_waitcnt lgkmcnt(0)" ::: "memory");                         \
    __builtin_amdgcn_s_barrier();

// ---------------- GEMM1: act = silu(x @ w1^T) * (x @ w3^T) ------------------
// Persistent, XCD-chunked nidx-major work order (T1): same-w13-panel tiles
// (adjacent ti, same nidx) are adjacent in w -> same XCD slab -> L2 hit
// instead of duplicate HBM fetch across non-coherent XCD L2s.
// Tile: 128 tok x 128 Brows ([0:32)=gate lo, [32:64)=up lo, [64:96)=gate hi,
// [96:128)=up hi). Wave (2Mx2N): 64 tok x 64 Brows -> acc[4][4].
__global__ __launch_bounds__(256, 3) void gemm1_kernel(
    const __bf16* __restrict__ xb, const float* __restrict__ w13,
    const int* __restrict__ tok, const int* __restrict__ cnt,
    const int* __restrict__ off, const int* __restrict__ tbl,
    unsigned short* __restrict__ act)
{
    __shared__ __bf16 As[2][4096];
    __shared__ __bf16 Bs[2][4096];
    const int tid  = threadIdx.x;
    const int wid  = tid >> 6;
    const int lane = tid & 63;
    const int wm = (wid >> 1) * 64;
    const int wn = (wid & 1);
    const int lrow = lane & 15;
    const int sr = tid >> 1;
    const int kh = tid & 1;
    const int wo = frag_off(sr, kh * 2);
    const int NS = H_DIM / BK;   // 64

    const int NT = tbl[0];
    const int W  = NT * 12;
    const int slab = (W + 7) >> 3;
    const int xcd  = blockIdx.x & 7;          // bid%8 == XCD (round-robin)
    const int jj   = blockIdx.x >> 3;         // 0..127 within XCD
    const int wlo  = xcd * slab;
    const int whi  = (wlo + slab) < W ? (wlo + slab) : W;
    for (int w = wlo + jj; w < whi; w += GRID_P / 8) {
        const int nidx = w / NT;              // nidx-major
        const int ti   = w - nidx * NT;
        const int ez = tbl[1 + ti];
        const int e  = ez >> 8;
        const int m0 = (ez & 255) * 128;
        const int c  = cnt[e];
        const int o  = off[e];
        const int n0 = nidx * 64;

        int rA = m0 + sr; rA = rA < c ? rA : c - 1;
        const __bf16* ap = xb + (size_t)tok[o + rA] * H_DIM + kh * 16;
        const int grp = sr >> 5;
        const int wrow = (grp & 1) * I_DIM + n0 + (grp >> 1) * 32 + (sr & 31);
        const float* wp = w13 + (size_t)e * (2 * I_DIM) * H_DIM
                              + (size_t)wrow * H_DIM + kh * 16;

        bf16x8 pa0_0, pa0_1, pa1_0, pa1_1;
        f32x4  pb0_0, pb0_1, pb0_2, pb0_3, pb1_0, pb1_1, pb1_2, pb1_3;
        f32x4  acc[4][4] = {};

        GEMM_PROLOGUE()

        int scur = 0;
        for (int it = 0; it < NS; it += 2) {
            GEMM_PHASE(0, 1)
            GEMM_PHASE(1, 0)
        }

        // epilogue: n=0,1 gate, n=2,3 up; icol = n0 + wn*32 + n*16 + lrow
#pragma unroll
        for (int m = 0; m < 4; ++m)
#pragma unroll
            for (int n = 0; n < 2; ++n)
#pragma unroll
                for (int i = 0; i < 4; ++i) {
                    const int row = m0 + wm + m * 16 + (lane >> 4) * 4 + i;
                    if (row < c) {
                        const int icol = n0 + wn * 32 + n * 16 + lrow;
                        const float g = acc[m][n][i];
                        const float u = acc[m][n + 2][i];
                        const float a = (g / (1.f + expf(-g))) * u;
                        act[(size_t)(o + row) * I_DIM + icol] =
                            __builtin_bit_cast(unsigned short, (__bf16)a);
                    }
                }
    }
}

// ---------------- GEMM2: ybuf[o+row] = wgt * (act @ w2^T), bf16 partials ----
// Persistent, XCD-chunked nidx-major. Tile: 128 tok x 128 H-cols. No atomics.
__global__ __launch_bounds__(256, 3) void gemm2_kernel(
    const unsigned short* __restrict__ act, const float* __restrict__ w2,
    const int* __restrict__ tok, const float* __restrict__ wgt,
    const int* __restrict__ cnt, const int* __restrict__ off,
    const int* __restrict__ tbl, unsigned short* __restrict__ ybuf)
{
    __shared__ __bf16 As[2][4096];
    __shared__ __bf16 Bs[2][4096];
    const int tid  = threadIdx.x;
    const int wid  = tid >> 6;
    const int lane = tid & 63;
    const int wm = (wid >> 1) * 64;
    const int wn = (wid & 1);
    const int lrow = lane & 15;
    const int sr = tid >> 1;
    const int kh = tid & 1;
    const int wo = frag_off(sr, kh * 2);
    const int NS = I_DIM / BK;   // 24

    const int NT = tbl[0];
    const int W  = NT * 16;
    const int slab = (W + 7) >> 3;
    const int xcd  = blockIdx.x & 7;
    const int jj   = blockIdx.x >> 3;
    const int wlo  = xcd * slab;
    const int whi  = (wlo + slab) < W ? (wlo + slab) : W;
    for (int w = wlo + jj; w < whi; w += GRID_P / 8) {
        const int nidx = w / NT;
        const int ti   = w - nidx * NT;
        const int ez = tbl[1 + ti];
        const int e  = ez >> 8;
        const int m0 = (ez & 255) * 128;
        const int c  = cnt[e];
        const int o  = off[e];
        const int n0 = nidx * 128;

        int rA = m0 + sr; rA = rA < c ? rA : c - 1;
        const __bf16* ap = (const __bf16*)act + (size_t)(o + rA) * I_DIM + kh * 16;
        const float* wp = w2 + (size_t)e * H_DIM * I_DIM
                             + (size_t)(n0 + sr) * I_DIM + kh * 16;

        bf16x8 pa0_0, pa0_1, pa1_0, pa1_1;
        f32x4  pb0_0, pb0_1, pb0_2, pb0_3, pb1_0, pb1_1, pb1_2, pb1_3;
        f32x4  acc[4][4] = {};

        GEMM_PROLOGUE()

        int scur = 0;
        for (int it = 0; it < NS; it += 2) {
            GEMM_PHASE(0, 1)
            GEMM_PHASE(1, 0)
        }

        // epilogue: weighted partial rows, bf16 stores (no RMW)
#pragma unroll
        for (int m = 0; m < 4; ++m)
#pragma unroll
            for (int i = 0; i < 4; ++i) {
                const int row = m0 + wm + m * 16 + (lane >> 4) * 4 + i;
                if (row < c) {
                    const float wv = wgt[o + row];
                    unsigned short* yr = ybuf + (size_t)(o + row) * H_DIM
                                              + n0 + wn * 64 + lrow;
#pragma unroll
                    for (int n = 0; n < 4; ++n)
                        yr[n * 16] = __builtin_bit_cast(
                            unsigned short, (__bf16)(wv * acc[m][n][i]));
                }
            }
    }
}

// ---------------- Combine: out[t] = sum_s ybuf[posl[t*8+s]] (bf16 -> f32) ---
__global__ __launch_bounds__(256) void combine_kernel(
    const unsigned short* __restrict__ ybuf, const int* __restrict__ posl,
    float* __restrict__ out)
{
    const int t = blockIdx.x;
    int p[K_TOP];
#pragma unroll
    for (int s = 0; s < K_TOP; ++s) p[s] = posl[t * K_TOP + s];
    const int h0 = threadIdx.x * 8;          // 256 threads x 8 = 2048 = H_DIM
    float a[8] = {};
#pragma unroll
    for (int s = 0; s < K_TOP; ++s) {
        const bf16x8 v = *(const bf16x8*)(ybuf + (size_t)p[s] * H_DIM + h0);
#pragma unroll
        for (int j = 0; j < 8; ++j) a[j] += (float)v[j];
    }
    f32x4 o0 = {a[0], a[1], a[2], a[3]};
    f32x4 o1 = {a[4], a[5], a[6], a[7]};
    *(f32x4*)(out + (size_t)t * H_DIM + h0)     = o0;
    *(f32x4*)(out + (size_t)t * H_DIM + h0 + 4) = o1;
}

// ---------------- Launch ----------------------------------------------------
extern "C" void kernel_launch(void* const* d_in, const int* in_sizes, int n_in,
                              void* d_out, int out_size, void* d_ws, size_t ws_size,
                              hipStream_t stream)
{
    const float* x   = (const float*)d_in[0];
    const float* gw  = (const float*)d_in[1];
    const float* w13 = (const float*)d_in[2];
    const float* w2  = (const float*)d_in[3];
    float* out = (float*)d_out;

    char* ws = (char*)d_ws;
    float*          wdense = (float*)(ws + 0x00000);
    unsigned int*   masks  = (unsigned int*)(ws + 0x20000);
    int*            cnt    = (int*)(ws + 0x21000);
    int*            off    = (int*)(ws + 0x21800);
    int*            tbl    = (int*)(ws + 0x22000);
    int*            tok    = (int*)(ws + 0x23000);
    float*          wgt    = (float*)(ws + 0x2B000);
    unsigned short* act    = (unsigned short*)(ws + 0x33000);    // 12.6 MB
    __bf16*         xb     = (__bf16*)(ws + 0xC40000);           // 4 MB
    int*            posl   = (int*)(ws + 0x1040000);             // 32 KB
    unsigned short* ybuf   = (unsigned short*)(ws + 0x1100000);  // 33.5 MB

    router_kernel<<<T_TOK, 256, 0, stream>>>(x, gw, wdense, masks, xb);
    route_kernel<<<1, 1024, 0, stream>>>(masks, wdense, cnt, off, tbl, tok, wgt, posl);
    gemm1_kernel<<<GRID_P, 256, 0, stream>>>(xb, w13, tok, cnt, off, tbl, act);
    gemm2_kernel<<<GRID_P, 256, 0, stream>>>(act, w2, tok, wgt, cnt, off, tbl, ybuf);
    combine_kernel<<<T_TOK, 256, 0, stream>>>(ybuf, posl, out);
}